// Round 2
// baseline (2464.040 us; speedup 1.0000x reference)
//
#include <hip/hip_runtime.h>
#include <math.h>

#define B_SZ 4096
#define D_SZ 1024
#define H_SZ 1024
#define T_SZ 50

typedef _Float16 f16;
typedef __attribute__((ext_vector_type(8))) _Float16 f16x8;
typedef __attribute__((ext_vector_type(4))) _Float16 f16x4;
typedef __attribute__((ext_vector_type(4))) float f32x4;
typedef __attribute__((ext_vector_type(4))) float f4;

__device__ __forceinline__ float fast_sigmoid(float x) {
    return 1.0f / (1.0f + __expf(-x));
}
__device__ __forceinline__ float fast_tanh(float x) {
    return 1.0f - 2.0f / (__expf(2.0f * x) + 1.0f);
}

// async global->LDS, 16 bytes per lane
__device__ __forceinline__ void gl_lds16(const void* g, void* l) {
    __builtin_amdgcn_global_load_lds(
        (const __attribute__((address_space(1))) unsigned int*)g,
        (__attribute__((address_space(3))) unsigned int*)l, 16, 0, 0);
}

#define BARX() do { __builtin_amdgcn_s_barrier(); asm volatile("" ::: "memory"); } while (0)
#define LGKM0() do { asm volatile("s_waitcnt lgkmcnt(0)" ::: "memory"); __builtin_amdgcn_sched_barrier(0); } while (0)

// ---------------------------------------------------------------------------
// fp32 -> fp16 conversion (4 elems/thread; n divisible by 4)
__global__ __launch_bounds__(256) void conv_kernel(
        const float* __restrict__ s, f16* __restrict__ d, int n) {
    int i = (blockIdx.x * 256 + threadIdx.x) * 4;
    if (i < n) {
        f4 v = *(const f4*)&s[i];
        f16x4 o = {(f16)v[0], (f16)v[1], (f16)v[2], (f16)v[3]};
        *(f16x4*)&d[i] = o;
    }
}

// ---------------------------------------------------------------------------
// Prepack w_hh (3H,H) f32 into per-(jblock,ktile) contiguous f16 tiles laid
// out exactly as the step kernel's LDS B image (slot XOR-swizzle included),
// so B staging is perfectly linear gl_lds. Tile = [192 rows][64 cols],
// row = g*64 + jj; element (row, col) stored at row*64 + ((col>>3)^(row&7))*8
// + (col&7). One-time cost.
__global__ __launch_bounds__(256) void prepack_kernel(
        const float* __restrict__ w, f16* __restrict__ wpk) {
    const int idx = blockIdx.x * 256 + threadIdx.x;  // 0..1535
    const int kt = blockIdx.y, jb = blockIdx.z;
    const int row = idx >> 3, s = idx & 7;           // row 0..191
    const int g = row >> 6, jj = row & 63;
    const int col = (s ^ (row & 7)) * 8;
    const float* src =
        w + ((size_t)(g << 10) + (jb << 6) + jj) * H_SZ + (kt << 6) + col;
    f4 v0 = *(const f4*)src;
    f4 v1 = *(const f4*)(src + 4);
    f16x8 o = {(f16)v0[0], (f16)v0[1], (f16)v0[2], (f16)v0[3],
               (f16)v1[0], (f16)v1[1], (f16)v1[2], (f16)v1[3]};
    *(f16x8*)&wpk[(size_t)(jb * 16 + kt) * 12288 + idx * 8] = o;
}

// ---------------------------------------------------------------------------
// h0 = tanh(ev @ w_init^T + b_init) via fp16 MFMA.
// Tile 128(M) x 64(N), 4 waves 2x2, wave 64x32 (4 mi x 2 ni frags 16x16x32).
__global__ __launch_bounds__(256, 2) void h0_kernel(
        const f16* __restrict__ ev, const f16* __restrict__ wi,
        const float* __restrict__ b_init, f16* __restrict__ hh) {
    __shared__ __align__(16) f16 lds[6144];  // A 128x32 @0, B 64x32 @4096
    const int tid = threadIdx.x;
    const int lane = tid & 63, wave = tid >> 6;
    const int b0 = blockIdx.y * 128, j0 = blockIdx.x * 64;
    const int wm = wave >> 1, wn = wave & 1;
    const int lrow = lane & 15, quad = lane >> 4;

    const f16* gsrc[3];
    int lbase[3];
    {
        const int row16 = lane >> 2, part = lane & 3;
#pragma unroll
        for (int i = 0; i < 3; ++i) {
            int c = wave + 4 * i;
            if (c < 8) {
                gsrc[i] = ev + (size_t)(b0 + c * 16 + row16) * D_SZ + part * 8;
                lbase[i] = c * 512;
            } else {
                int cc = c - 8;
                gsrc[i] = wi + (size_t)(j0 + cc * 16 + row16) * D_SZ + part * 8;
                lbase[i] = 4096 + cc * 512;
            }
        }
    }

    int offA[4], offB[2];
#pragma unroll
    for (int mi = 0; mi < 4; ++mi)
        offA[mi] = (wm * 64 + mi * 16 + lrow) * 32 + quad * 8;
#pragma unroll
    for (int ni = 0; ni < 2; ++ni)
        offB[ni] = 4096 + (wn * 32 + ni * 16 + lrow) * 32 + quad * 8;

    f32x4 acc[4][2] = {};

    for (int k0 = 0; k0 < D_SZ; k0 += 32) {
        __syncthreads();
#pragma unroll
        for (int i = 0; i < 3; ++i)
            gl_lds16(gsrc[i] + k0, &lds[lbase[i]] + lane * 8);
        __syncthreads();
        f16x8 aa[4], bb[2];
#pragma unroll
        for (int mi = 0; mi < 4; ++mi) aa[mi] = *(const f16x8*)&lds[offA[mi]];
#pragma unroll
        for (int ni = 0; ni < 2; ++ni) bb[ni] = *(const f16x8*)&lds[offB[ni]];
#pragma unroll
        for (int mi = 0; mi < 4; ++mi)
#pragma unroll
            for (int ni = 0; ni < 2; ++ni)
                acc[mi][ni] = __builtin_amdgcn_mfma_f32_16x16x32_f16(
                    aa[mi], bb[ni], acc[mi][ni], 0, 0, 0);
    }

#pragma unroll
    for (int ni = 0; ni < 2; ++ni) {
        const int j = j0 + wn * 32 + ni * 16 + lrow;
        const float bj = b_init[j];
#pragma unroll
        for (int mi = 0; mi < 4; ++mi)
#pragma unroll
            for (int reg = 0; reg < 4; ++reg) {
                const int b = b0 + wm * 64 + mi * 16 + quad * 4 + reg;
                hh[(size_t)b * H_SZ + j] = (f16)tanhf(acc[mi][ni][reg] + bj);
            }
    }
}

// ---------------------------------------------------------------------------
// One GRU step v3 — 8-phase-style schedule (T2+T3+T4+T5):
// 512 threads = 8 waves (4M x 2N); tile 256(M) x 192(N = 3 gates x 64 j),
// BK=64, grid 16x16 = 256 blocks = exactly 1 block/CU.
// Per K-tile: 4 phases of {ds_read subtile || issue stage chunk -> barrier
// -> lgkmcnt(0) -> setprio(1) + 12 MFMA -> barrier}; counted vmcnt(2)/(1)
// twice per tile, NEVER 0 in the main loop (chunks: S0=A rows 0-127,
// S1=A rows 128-255, S2=B rows 0-127, S3=B rows 128-191; issued ph0..ph3,
// consumed one tile later -> 4-7 loads in flight spanning 2-4 phases).
// LDS image XOR-swizzled (slot ^= row&7) -> ds_read_b128 is uniform
// 8-lanes-per-bank-group (the b128 minimum). A source addrs carry the
// inverse swizzle; B comes pre-swizzled from prepack (linear staging).
// LDS: 2 x 56 KB = 112 KB.
__global__ __launch_bounds__(512, 1) void step_kernel(
        const f16* __restrict__ hh, const f16* __restrict__ wpk,
        const float* __restrict__ b_hh, const float* __restrict__ w_ih,
        const float* __restrict__ b_ih, const float* __restrict__ w_out,
        const float* __restrict__ teach, f16* __restrict__ nhh,
        float* __restrict__ out, int step_t) {
    constexpr int BUFE = 28672;  // elems per buffer (A 16384 + B 12288)
    __shared__ __align__(16) f16 lds[2 * BUFE];  // 112 KB
    const int tid = threadIdx.x;
    const int lane = tid & 63, wave = tid >> 6;
    const int wm = wave >> 1, wn = wave & 1;  // wm 0..3, wn 0..1
    const int b0 = blockIdx.y * 256, j0 = blockIdx.x * 64;
    const int lrow = lane & 15, quad = lane >> 4;

    // ---- staging sources ----
    const f16* ga[4];
    int la[4];
    {
        const int r8 = tid >> 3, s8 = tid & 7;
#pragma unroll
        for (int i = 0; i < 4; ++i) {
            const int row = i * 64 + r8;  // 0..255
            ga[i] = hh + (size_t)(b0 + row) * H_SZ + ((s8 ^ (row & 7)) * 8);
            la[i] = i * 4096 + tid * 8;
        }
    }
    const f16* gb[3];
    int lb[3];
    {
        const f16* wt = wpk + (size_t)blockIdx.x * 16 * 12288;
#pragma unroll
        for (int i = 0; i < 3; ++i) {
            gb[i] = wt + (size_t)(i * 512 + tid) * 8;
            lb[i] = 16384 + (i * 512 + tid) * 8;
        }
    }

    // ---- fragment read offsets (swizzled) ----
    int offA[2][4], offB[2][6];
#pragma unroll
    for (int ks = 0; ks < 2; ++ks) {
        const int sw = ((ks * 4 + quad) ^ (lrow & 7)) * 8;
#pragma unroll
        for (int mi = 0; mi < 4; ++mi)
            offA[ks][mi] = (wm * 64 + mi * 16 + lrow) * 64 + sw;
#pragma unroll
        for (int f = 0; f < 6; ++f) {
            const int g = f >> 1, ni = f & 1;
            offB[ks][f] = 16384 + (g * 64 + wn * 32 + ni * 16 + lrow) * 64 + sw;
        }
    }

    f32x4 acc[3][4][2] = {};
    f16x8 aa[4], bv[3];

    auto issueA = [&](int kt, int i) {
        gl_lds16(ga[i] + kt * 64, &lds[((kt & 1) ? BUFE : 0) + la[i]]);
    };
    auto issueB = [&](int kt, int i) {
        gl_lds16(gb[i] + (size_t)kt * 12288, &lds[((kt & 1) ? BUFE : 0) + lb[i]]);
    };
    auto rdA = [&](int rb, int ks) {
#pragma unroll
        for (int mi = 0; mi < 4; ++mi)
            aa[mi] = *(const f16x8*)&lds[rb + offA[ks][mi]];
    };
    auto rdB = [&](int rb, int ks, int f0_) {
#pragma unroll
        for (int f = 0; f < 3; ++f)
            bv[f] = *(const f16x8*)&lds[rb + offB[ks][f0_ + f]];
    };
    auto mm = [&](int f0_) {
#pragma unroll
        for (int f = 0; f < 3; ++f) {
            const int ff = f0_ + f;
            const int g = ff >> 1, ni = ff & 1;
#pragma unroll
            for (int mi = 0; mi < 4; ++mi)
                acc[g][mi][ni] = __builtin_amdgcn_mfma_f32_16x16x32_f16(
                    aa[mi], bv[f], acc[g][mi][ni], 0, 0, 0);
        }
    };

    // ---- prologue: tile 0 fully in flight; certify S0-S2 then enter ----
#pragma unroll
    for (int i = 0; i < 4; ++i) issueA(0, i);
#pragma unroll
    for (int i = 0; i < 3; ++i) issueB(0, i);
    asm volatile("s_waitcnt vmcnt(1)" ::: "memory");
    BARX();

    for (int tt = 0; tt < 16; ++tt) {
        const int rb = (tt & 1) * BUFE;
        const bool pf = tt < 15;
        const int tn = tt + 1;
        // ph0: ks0, frags 0-2 (needs S0,S1,S2 of tt — certified)
        rdA(rb, 0);
        rdB(rb, 0, 0);
        if (pf) { issueA(tn, 0); issueA(tn, 1); }
        BARX();
        LGKM0();
        __builtin_amdgcn_s_setprio(1);
        mm(0);
        __builtin_amdgcn_s_setprio(0);
        if (pf) asm volatile("s_waitcnt vmcnt(2)" ::: "memory");  // S3(tt) done
        else    asm volatile("s_waitcnt vmcnt(0)" ::: "memory");
        BARX();
        // ph1: ks0, frags 3-5 (f4,f5 need S3 — just certified)
        rdB(rb, 0, 3);
        if (pf) { issueA(tn, 2); issueA(tn, 3); }
        BARX();
        LGKM0();
        __builtin_amdgcn_s_setprio(1);
        mm(3);
        __builtin_amdgcn_s_setprio(0);
        BARX();
        // ph2: ks1, frags 0-2 (same chunks, other k-half)
        rdA(rb, 1);
        rdB(rb, 1, 0);
        if (pf) { issueB(tn, 0); issueB(tn, 1); }
        BARX();
        LGKM0();
        __builtin_amdgcn_s_setprio(1);
        mm(0);
        __builtin_amdgcn_s_setprio(0);
        BARX();
        // ph3: ks1, frags 3-5
        rdB(rb, 1, 3);
        if (pf) issueB(tn, 2);
        BARX();
        LGKM0();
        __builtin_amdgcn_s_setprio(1);
        mm(3);
        __builtin_amdgcn_s_setprio(0);
        if (pf) asm volatile("s_waitcnt vmcnt(1)" ::: "memory");  // S0-S2(tn) done
        BARX();
    }

    // -------- fused epilogue: gates, h_next, delta partials --------
    float p0[4][4], p1[4][4];
#pragma unroll
    for (int mi = 0; mi < 4; ++mi)
#pragma unroll
        for (int reg = 0; reg < 4; ++reg) {
            const int b = b0 + wm * 64 + mi * 16 + quad * 4 + reg;
            if (step_t > 0) {
                p0[mi][reg] = teach[b * (T_SZ * 2) + (step_t - 1) * 2 + 0];
                p1[mi][reg] = teach[b * (T_SZ * 2) + (step_t - 1) * 2 + 1];
            } else {
                p0[mi][reg] = 0.f;
                p1[mi][reg] = 0.f;
            }
        }

    float s0[4][4] = {}, s1[4][4] = {};
#pragma unroll
    for (int ni = 0; ni < 2; ++ni) {
        const int j = j0 + wn * 32 + ni * 16 + lrow;
        const float wr0 = w_ih[(0 * H_SZ + j) * 2 + 0];
        const float wr1 = w_ih[(0 * H_SZ + j) * 2 + 1];
        const float wz0 = w_ih[(1 * H_SZ + j) * 2 + 0];
        const float wz1 = w_ih[(1 * H_SZ + j) * 2 + 1];
        const float wn0 = w_ih[(2 * H_SZ + j) * 2 + 0];
        const float wn1 = w_ih[(2 * H_SZ + j) * 2 + 1];
        const float br = b_ih[0 * H_SZ + j] + b_hh[0 * H_SZ + j];
        const float bz = b_ih[1 * H_SZ + j] + b_hh[1 * H_SZ + j];
        const float bn = b_ih[2 * H_SZ + j];
        const float hbn = b_hh[2 * H_SZ + j];
        const float wo0 = w_out[j], wo1 = w_out[H_SZ + j];
#pragma unroll
        for (int mi = 0; mi < 4; ++mi) {
#pragma unroll
            for (int reg = 0; reg < 4; ++reg) {
                const int b = b0 + wm * 64 + mi * 16 + quad * 4 + reg;
                const float hr = acc[0][mi][ni][reg];
                const float hz = acc[1][mi][ni][reg];
                const float hn_ = acc[2][mi][ni][reg] + hbn;
                const float xr = wr0 * p0[mi][reg] + wr1 * p1[mi][reg] + br;
                const float xz = wz0 * p0[mi][reg] + wz1 * p1[mi][reg] + bz;
                const float xn = wn0 * p0[mi][reg] + wn1 * p1[mi][reg] + bn;
                const float r = fast_sigmoid(xr + hr);
                const float z = fast_sigmoid(xz + hz);
                const float n = fast_tanh(xn + r * hn_);
                const size_t idx = (size_t)b * H_SZ + j;
                const float hold = (float)hh[idx];
                const float hnew = (1.0f - z) * n + z * hold;
                nhh[idx] = (f16)hnew;
                s0[mi][reg] += hnew * wo0;
                s1[mi][reg] += hnew * wo1;
            }
        }
    }
#pragma unroll
    for (int mi = 0; mi < 4; ++mi)
#pragma unroll
        for (int reg = 0; reg < 4; ++reg) {
            float a = s0[mi][reg], c = s1[mi][reg];
#pragma unroll
            for (int m = 1; m < 16; m <<= 1) {
                a += __shfl_xor(a, m);
                c += __shfl_xor(c, m);
            }
            if (lrow == 0) {
                const int b = b0 + wm * 64 + mi * 16 + quad * 4 + reg;
                atomicAdd(&out[b * (T_SZ * 2) + step_t * 2 + 0], a);
                atomicAdd(&out[b * (T_SZ * 2) + step_t * 2 + 1], c);
            }
        }
}

// ---------------------------------------------------------------------------
// pred_deltas += b_out; pred_pos = cumsum
__global__ __launch_bounds__(256) void final_kernel(
        float* __restrict__ out, float* __restrict__ pos,
        const float* __restrict__ b_out) {
    int idx = blockIdx.x * 256 + threadIdx.x;  // b*2 + c
    if (idx >= B_SZ * 2) return;
    int b = idx >> 1, c = idx & 1;
    float bc = b_out[c];
    float acc = 0.0f;
    for (int t = 0; t < T_SZ; ++t) {
        float d = out[b * (T_SZ * 2) + t * 2 + c] + bc;
        out[b * (T_SZ * 2) + t * 2 + c] = d;
        acc += d;
        pos[b * (T_SZ * 2) + t * 2 + c] = acc;
    }
}

// ---------------------------------------------------------------------------
extern "C" void kernel_launch(void* const* d_in, const int* in_sizes, int n_in,
                              void* d_out, int out_size, void* d_ws, size_t ws_size,
                              hipStream_t stream) {
    const float* ev     = (const float*)d_in[0];
    const float* teach  = (const float*)d_in[1];
    const float* w_init = (const float*)d_in[2];
    const float* b_init = (const float*)d_in[3];
    const float* w_ih   = (const float*)d_in[4];
    const float* w_hh   = (const float*)d_in[5];
    const float* b_ih   = (const float*)d_in[6];
    const float* b_hh   = (const float*)d_in[7];
    const float* w_out  = (const float*)d_in[8];
    const float* b_out  = (const float*)d_in[9];

    float* out = (float*)d_out;                  // pred_deltas (B,T,2)
    float* pos = out + (size_t)B_SZ * T_SZ * 2;  // pred_pos    (B,T,2)

    // ws layout (f16 units): hA (4M), hB (4M), wpk (3M), w_init (1M).
    // ev_f16 (4M) aliases hB (consumed by h0 before hB is first written).
    f16* ws = (f16*)d_ws;
    f16* hA    = ws;
    f16* hB    = hA + (size_t)B_SZ * H_SZ;
    f16* wpk   = hB + (size_t)B_SZ * H_SZ;
    f16* winit = wpk + (size_t)3 * H_SZ * H_SZ;
    f16* evf   = hB;  // alias

    hipMemsetAsync(out, 0, (size_t)B_SZ * T_SZ * 2 * sizeof(float), stream);

    conv_kernel<<<(H_SZ * D_SZ) / 1024, 256, 0, stream>>>(w_init, winit, H_SZ * D_SZ);
    conv_kernel<<<(B_SZ * D_SZ) / 1024, 256, 0, stream>>>(ev, evf, B_SZ * D_SZ);
    prepack_kernel<<<dim3(6, 16, 16), 256, 0, stream>>>(w_hh, wpk);

    dim3 g0(H_SZ / 64, B_SZ / 128);  // (16, 32)
    h0_kernel<<<g0, 256, 0, stream>>>(evf, winit, b_init, hA);

    dim3 gs(H_SZ / 64, B_SZ / 256);  // (16, 16) = 256 blocks = 1 block/CU
    f16 *hc = hA, *hn = hB;
    for (int t = 0; t < T_SZ; ++t) {
        step_kernel<<<gs, 512, 0, stream>>>(hc, wpk, b_hh, w_ih, b_ih, w_out,
                                            teach, hn, out, t);
        f16* tmp = hc; hc = hn; hn = tmp;
    }
    final_kernel<<<(B_SZ * 2 + 255) / 256, 256, 0, stream>>>(out, pos, b_out);
}

// Round 3
// 1987.625 us; speedup vs baseline: 1.2397x; 1.2397x over previous
//
#include <hip/hip_runtime.h>
#include <math.h>

#define B_SZ 4096
#define D_SZ 1024
#define H_SZ 1024
#define T_SZ 50

typedef _Float16 f16;
typedef __attribute__((ext_vector_type(8))) _Float16 f16x8;
typedef __attribute__((ext_vector_type(4))) _Float16 f16x4;
typedef __attribute__((ext_vector_type(2))) _Float16 f16x2;
typedef __attribute__((ext_vector_type(4))) float f32x4;
typedef __attribute__((ext_vector_type(4))) float f4;

__device__ __forceinline__ float fast_sigmoid(float x) {
    return 1.0f / (1.0f + __expf(-x));
}
__device__ __forceinline__ float fast_tanh(float x) {
    return 1.0f - 2.0f / (__expf(2.0f * x) + 1.0f);
}

// async global->LDS, 16 bytes per lane
__device__ __forceinline__ void gl_lds16(const void* g, void* l) {
    __builtin_amdgcn_global_load_lds(
        (const __attribute__((address_space(1))) unsigned int*)g,
        (__attribute__((address_space(3))) unsigned int*)l, 16, 0, 0);
}

#define LGKM0() do { asm volatile("s_waitcnt lgkmcnt(0)" ::: "memory"); __builtin_amdgcn_sched_barrier(0); } while (0)

// ---------------------------------------------------------------------------
// fp32 -> fp16 conversion (4 elems/thread; n divisible by 4)
__global__ __launch_bounds__(256) void conv_kernel(
        const float* __restrict__ s, f16* __restrict__ d, int n) {
    int i = (blockIdx.x * 256 + threadIdx.x) * 4;
    if (i < n) {
        f4 v = *(const f4*)&s[i];
        f16x4 o = {(f16)v[0], (f16)v[1], (f16)v[2], (f16)v[3]};
        *(f16x4*)&d[i] = o;
    }
}

// ---------------------------------------------------------------------------
// teach (B,T,2) f32 -> tT (T,B,2) f16: coalesced per-step epilogue reads.
__global__ __launch_bounds__(256) void ttrans_kernel(
        const float* __restrict__ teach, f16* __restrict__ tT) {
    int idx = blockIdx.x * 256 + threadIdx.x;  // t*B + b
    if (idx >= T_SZ * B_SZ) return;
    int t = idx >> 12, b = idx & 4095;
    float v0 = teach[b * (T_SZ * 2) + t * 2 + 0];
    float v1 = teach[b * (T_SZ * 2) + t * 2 + 1];
    f16x2 o = {(f16)v0, (f16)v1};
    *(f16x2*)&tT[(size_t)idx * 2] = o;
}

// ---------------------------------------------------------------------------
// Prepack w_hh (3H,H) f32 into per-(jblock, kt32) tiles [192 rows][32 cols]
// f16, with the LDS slot swizzle (slot ^= (row>>1)&3 on 8-elem slots) baked
// in, so step-kernel B staging is perfectly linear gl_lds.
__global__ __launch_bounds__(256) void prepack_kernel(
        const float* __restrict__ w, f16* __restrict__ wpk) {
    const int idx = blockIdx.x * 256 + threadIdx.x;  // 0..767 (row,slot)
    const int kt = blockIdx.y, jb = blockIdx.z;
    const int row = idx >> 2, s = idx & 3;           // row 0..191
    const int g = row >> 6, jj = row & 63;
    const int col = (kt << 5) + ((s ^ ((row >> 1) & 3)) << 3);
    const float* src =
        w + ((size_t)(g << 10) + (jb << 6) + jj) * H_SZ + col;
    f4 v0 = *(const f4*)src;
    f4 v1 = *(const f4*)(src + 4);
    f16x8 o = {(f16)v0[0], (f16)v0[1], (f16)v0[2], (f16)v0[3],
               (f16)v1[0], (f16)v1[1], (f16)v1[2], (f16)v1[3]};
    *(f16x8*)&wpk[((size_t)jb * 32 + kt) * 6144 + idx * 8] = o;
}

// ---------------------------------------------------------------------------
// h0 = tanh(ev @ w_init^T + b_init) via fp16 MFMA.
__global__ __launch_bounds__(256, 2) void h0_kernel(
        const f16* __restrict__ ev, const f16* __restrict__ wi,
        const float* __restrict__ b_init, f16* __restrict__ hh) {
    __shared__ __align__(16) f16 lds[6144];  // A 128x32 @0, B 64x32 @4096
    const int tid = threadIdx.x;
    const int lane = tid & 63, wave = tid >> 6;
    const int b0 = blockIdx.y * 128, j0 = blockIdx.x * 64;
    const int wm = wave >> 1, wn = wave & 1;
    const int lrow = lane & 15, quad = lane >> 4;

    const f16* gsrc[3];
    int lbase[3];
    {
        const int row16 = lane >> 2, part = lane & 3;
#pragma unroll
        for (int i = 0; i < 3; ++i) {
            int c = wave + 4 * i;
            if (c < 8) {
                gsrc[i] = ev + (size_t)(b0 + c * 16 + row16) * D_SZ + part * 8;
                lbase[i] = c * 512;
            } else {
                int cc = c - 8;
                gsrc[i] = wi + (size_t)(j0 + cc * 16 + row16) * D_SZ + part * 8;
                lbase[i] = 4096 + cc * 512;
            }
        }
    }

    int offA[4], offB[2];
#pragma unroll
    for (int mi = 0; mi < 4; ++mi)
        offA[mi] = (wm * 64 + mi * 16 + lrow) * 32 + quad * 8;
#pragma unroll
    for (int ni = 0; ni < 2; ++ni)
        offB[ni] = 4096 + (wn * 32 + ni * 16 + lrow) * 32 + quad * 8;

    f32x4 acc[4][2] = {};

    for (int k0 = 0; k0 < D_SZ; k0 += 32) {
        __syncthreads();
#pragma unroll
        for (int i = 0; i < 3; ++i)
            gl_lds16(gsrc[i] + k0, &lds[lbase[i]] + lane * 8);
        __syncthreads();
        f16x8 aa[4], bb[2];
#pragma unroll
        for (int mi = 0; mi < 4; ++mi) aa[mi] = *(const f16x8*)&lds[offA[mi]];
#pragma unroll
        for (int ni = 0; ni < 2; ++ni) bb[ni] = *(const f16x8*)&lds[offB[ni]];
#pragma unroll
        for (int mi = 0; mi < 4; ++mi)
#pragma unroll
            for (int ni = 0; ni < 2; ++ni)
                acc[mi][ni] = __builtin_amdgcn_mfma_f32_16x16x32_f16(
                    aa[mi], bb[ni], acc[mi][ni], 0, 0, 0);
    }

#pragma unroll
    for (int ni = 0; ni < 2; ++ni) {
        const int j = j0 + wn * 32 + ni * 16 + lrow;
        const float bj = b_init[j];
#pragma unroll
        for (int mi = 0; mi < 4; ++mi)
#pragma unroll
            for (int reg = 0; reg < 4; ++reg) {
                const int b = b0 + wm * 64 + mi * 16 + quad * 4 + reg;
                hh[(size_t)b * H_SZ + j] = (f16)tanhf(acc[mi][ni][reg] + bj);
            }
    }
}

// ---------------------------------------------------------------------------
// One GRU step v4: deep-pipelined fp16 MFMA GEMM, BM=256 x BN=192 x BK=32.
// 512 threads = 8 waves (4M x 2N); grid 256 = 1 block/CU, XCD-swizzled.
// 5 LDS buffers (5 x 28 KB = 140 KB), prefetch distance = 4 K-tiles
// (~1400 cyc — covers cold-L2 miss latency; each dispatch starts L2-cold).
// ONE barrier per tile, counted s_waitcnt vmcnt(21) (=3 tiles in flight),
// vmcnt reaches 0 only on the last tile. Staging by waves 0-3 only.
// LDS slot-swizzle (slot ^= (row>>1)&3): ds_read_b128 is 2-way (free).
// Atomics replaced by per-jblock partial-delta buffers (ping-pong),
// reduced at the start of the NEXT step's dispatch by the bx==0 blocks.
__global__ __launch_bounds__(512, 1) void step_kernel(
        const f16* __restrict__ hh, const f16* __restrict__ wpk,
        const float* __restrict__ b_hh, const float* __restrict__ w_ih,
        const float* __restrict__ b_ih, const float* __restrict__ w_out,
        const f16* __restrict__ tT, f16* __restrict__ nhh,
        float* __restrict__ out, const float* __restrict__ partP,
        float* __restrict__ partC, int step_t) {
    constexpr int TILE_E = 14336;  // f16/buffer: A 256x32=8192 + B 192x32=6144
    __shared__ __align__(16) f16 lds[5 * TILE_E];  // 140 KB
    const int tid = threadIdx.x;
    const int lane = tid & 63, wave = tid >> 6;
    const int wm = wave >> 1, wn = wave & 1;
    // XCD-aware swizzle: each XCD owns an 8bx x 4by patch (id%8 = XCD).
    const int id = blockIdx.x;
    const int xcd = id & 7, slot = id >> 3;
    const int bx = (xcd & 1) * 8 + (slot & 7);
    const int by = (xcd >> 1) * 4 + (slot >> 3);
    const int b0 = by * 256, j0 = bx * 64;
    const int lrow = lane & 15, quad = lane >> 4;

    // ---- reduce previous step's delta partials (16 bx==0 blocks) ----
    // Strictly BEFORE any gl_lds issue, so vmcnt FIFO math stays valid
    // (these older ops retire first).
    if (step_t > 0 && bx == 0) {
        const int rr = tid >> 1, cc = tid & 1;
        const int b = b0 + rr;
        float s = 0.f;
#pragma unroll
        for (int x = 0; x < 16; ++x) s += partP[x * 8192 + b * 2 + cc];
        out[b * (T_SZ * 2) + (step_t - 1) * 2 + cc] = s;
    }

    // ---- staging sources (waves 0-3; 7 gl_lds per wave per tile) ----
    const f16* ga[4];
    const f16* gb;
    {
        const int r = tid >> 2;
        const int cs = ((tid & 3) ^ ((tid >> 3) & 3)) * 8;  // inverse swizzle
#pragma unroll
        for (int i = 0; i < 4; ++i)
            ga[i] = hh + (size_t)(b0 + i * 64 + r) * H_SZ + cs;
        gb = wpk + (size_t)bx * (32 * 6144);
    }
    auto issueT = [&](int kt, int sb) {
        if (tid < 256) {
#pragma unroll
            for (int i = 0; i < 4; ++i)
                gl_lds16(ga[i] + kt * 32, &lds[sb + i * 2048 + tid * 8]);
#pragma unroll
            for (int i = 0; i < 3; ++i)
                gl_lds16(gb + kt * 6144 + i * 2048 + tid * 8,
                         &lds[sb + 8192 + i * 2048 + tid * 8]);
        }
    };

    // ---- fragment read offsets (swizzled; 2-way bank aliasing = free) ----
    const int swz = (quad ^ ((lrow >> 1) & 3)) * 8;
    int offA[4], offB[6];
#pragma unroll
    for (int mi = 0; mi < 4; ++mi)
        offA[mi] = (wm * 64 + mi * 16 + lrow) * 32 + swz;
#pragma unroll
    for (int f = 0; f < 6; ++f)
        offB[f] = 8192 + ((f >> 1) * 64 + wn * 32 + (f & 1) * 16 + lrow) * 32 + swz;

    f32x4 acc[3][4][2] = {};

    // ---- prologue: 4 tiles in flight ----
    issueT(0, 0);
    issueT(1, TILE_E);
    issueT(2, 2 * TILE_E);
    issueT(3, 3 * TILE_E);

    int rb = 0, sb = 4 * TILE_E;
    for (int tt = 0; tt < 32; ++tt) {
        // certify tile tt landed (7 loads); keep the rest in flight
        if (tt < 29)       asm volatile("s_waitcnt vmcnt(21)" ::: "memory");
        else if (tt == 29) asm volatile("s_waitcnt vmcnt(14)" ::: "memory");
        else if (tt == 30) asm volatile("s_waitcnt vmcnt(7)" ::: "memory");
        else               asm volatile("s_waitcnt vmcnt(0)" ::: "memory");
        __builtin_amdgcn_s_barrier();
        asm volatile("" ::: "memory");
        f16x8 aa[4], bv[6];
#pragma unroll
        for (int mi = 0; mi < 4; ++mi)
            aa[mi] = *(const f16x8*)&lds[rb + offA[mi]];
#pragma unroll
        for (int f = 0; f < 6; ++f)
            bv[f] = *(const f16x8*)&lds[rb + offB[f]];
        if (tt < 28) issueT(tt + 4, sb);  // overwrites tile tt-1's buffer: safe
        LGKM0();
        __builtin_amdgcn_s_setprio(1);
#pragma unroll
        for (int f = 0; f < 6; ++f) {
            const int g = f >> 1, ni = f & 1;
#pragma unroll
            for (int mi = 0; mi < 4; ++mi)
                acc[g][mi][ni] = __builtin_amdgcn_mfma_f32_16x16x32_f16(
                    aa[mi], bv[f], acc[g][mi][ni], 0, 0, 0);
        }
        __builtin_amdgcn_s_setprio(0);
        rb += TILE_E; if (rb == 5 * TILE_E) rb = 0;
        sb += TILE_E; if (sb == 5 * TILE_E) sb = 0;
    }

    // -------- fused epilogue: gates, h_next, delta partials --------
    float p0[4][4], p1[4][4];
#pragma unroll
    for (int mi = 0; mi < 4; ++mi)
#pragma unroll
        for (int reg = 0; reg < 4; ++reg) {
            const int b = b0 + wm * 64 + mi * 16 + quad * 4 + reg;
            if (step_t > 0) {
                f16x2 tv = *(const f16x2*)&tT[((size_t)(step_t - 1) * B_SZ + b) * 2];
                p0[mi][reg] = (float)tv[0];
                p1[mi][reg] = (float)tv[1];
            } else {
                p0[mi][reg] = 0.f;
                p1[mi][reg] = 0.f;
            }
        }

    float s0[4][4] = {}, s1[4][4] = {};
#pragma unroll
    for (int ni = 0; ni < 2; ++ni) {
        const int j = j0 + wn * 32 + ni * 16 + lrow;
        const float wr0 = w_ih[(0 * H_SZ + j) * 2 + 0];
        const float wr1 = w_ih[(0 * H_SZ + j) * 2 + 1];
        const float wz0 = w_ih[(1 * H_SZ + j) * 2 + 0];
        const float wz1 = w_ih[(1 * H_SZ + j) * 2 + 1];
        const float wn0 = w_ih[(2 * H_SZ + j) * 2 + 0];
        const float wn1 = w_ih[(2 * H_SZ + j) * 2 + 1];
        const float br = b_ih[0 * H_SZ + j] + b_hh[0 * H_SZ + j];
        const float bz = b_ih[1 * H_SZ + j] + b_hh[1 * H_SZ + j];
        const float bn = b_ih[2 * H_SZ + j];
        const float hbn = b_hh[2 * H_SZ + j];
        const float wo0 = w_out[j], wo1 = w_out[H_SZ + j];
#pragma unroll
        for (int mi = 0; mi < 4; ++mi) {
#pragma unroll
            for (int reg = 0; reg < 4; ++reg) {
                const int b = b0 + wm * 64 + mi * 16 + quad * 4 + reg;
                const float hr = acc[0][mi][ni][reg];
                const float hz = acc[1][mi][ni][reg];
                const float hn_ = acc[2][mi][ni][reg] + hbn;
                const float xr = wr0 * p0[mi][reg] + wr1 * p1[mi][reg] + br;
                const float xz = wz0 * p0[mi][reg] + wz1 * p1[mi][reg] + bz;
                const float xn = wn0 * p0[mi][reg] + wn1 * p1[mi][reg] + bn;
                const float r = fast_sigmoid(xr + hr);
                const float z = fast_sigmoid(xz + hz);
                const float n = fast_tanh(xn + r * hn_);
                const size_t idx = (size_t)b * H_SZ + j;
                const float hold = (float)hh[idx];
                const float hnew = (1.0f - z) * n + z * hold;
                nhh[idx] = (f16)hnew;
                s0[mi][reg] += hnew * wo0;
                s1[mi][reg] += hnew * wo1;
            }
        }
    }

    // per-wave lrow-reduction, then cross-wn merge via LDS, store partials
    float ra[4][4], rc[4][4];
#pragma unroll
    for (int mi = 0; mi < 4; ++mi)
#pragma unroll
        for (int reg = 0; reg < 4; ++reg) {
            float a = s0[mi][reg], c = s1[mi][reg];
#pragma unroll
            for (int m = 1; m < 16; m <<= 1) {
                a += __shfl_xor(a, m);
                c += __shfl_xor(c, m);
            }
            ra[mi][reg] = a;
            rc[mi][reg] = c;
        }
    float* red = (float*)lds;  // 2 KB scratch; K-loop LDS fully consumed
    if (wn == 1 && lrow == 0) {
#pragma unroll
        for (int mi = 0; mi < 4; ++mi)
#pragma unroll
            for (int reg = 0; reg < 4; ++reg) {
                const int key = wm * 64 + mi * 16 + quad * 4 + reg;
                red[key * 2 + 0] = ra[mi][reg];
                red[key * 2 + 1] = rc[mi][reg];
            }
    }
    __syncthreads();
    if (wn == 0 && lrow == 0) {
#pragma unroll
        for (int mi = 0; mi < 4; ++mi)
#pragma unroll
            for (int reg = 0; reg < 4; ++reg) {
                const int key = wm * 64 + mi * 16 + quad * 4 + reg;
                const int b = b0 + key;
                partC[bx * 8192 + b * 2 + 0] = ra[mi][reg] + red[key * 2 + 0];
                partC[bx * 8192 + b * 2 + 1] = rc[mi][reg] + red[key * 2 + 1];
            }
    }
}

// ---------------------------------------------------------------------------
// pred_deltas += b_out (t<49 already reduced into out); t=49 reduced here
// from the last partial buffer; pred_pos = cumsum.
__global__ __launch_bounds__(256) void final_kernel(
        float* __restrict__ out, float* __restrict__ pos,
        const float* __restrict__ b_out, const float* __restrict__ partLast) {
    int idx = blockIdx.x * 256 + threadIdx.x;  // b*2 + c
    if (idx >= B_SZ * 2) return;
    int b = idx >> 1, c = idx & 1;
    float bc = b_out[c];
    float acc = 0.0f;
    for (int t = 0; t < T_SZ - 1; ++t) {
        float d = out[b * (T_SZ * 2) + t * 2 + c] + bc;
        out[b * (T_SZ * 2) + t * 2 + c] = d;
        acc += d;
        pos[b * (T_SZ * 2) + t * 2 + c] = acc;
    }
    float s = 0.f;
#pragma unroll
    for (int x = 0; x < 16; ++x) s += partLast[x * 8192 + b * 2 + c];
    float d = s + bc;
    out[b * (T_SZ * 2) + (T_SZ - 1) * 2 + c] = d;
    acc += d;
    pos[b * (T_SZ * 2) + (T_SZ - 1) * 2 + c] = acc;
}

// ---------------------------------------------------------------------------
extern "C" void kernel_launch(void* const* d_in, const int* in_sizes, int n_in,
                              void* d_out, int out_size, void* d_ws, size_t ws_size,
                              hipStream_t stream) {
    const float* ev     = (const float*)d_in[0];
    const float* teach  = (const float*)d_in[1];
    const float* w_init = (const float*)d_in[2];
    const float* b_init = (const float*)d_in[3];
    const float* w_ih   = (const float*)d_in[4];
    const float* w_hh   = (const float*)d_in[5];
    const float* b_ih   = (const float*)d_in[6];
    const float* b_hh   = (const float*)d_in[7];
    const float* w_out  = (const float*)d_in[8];
    const float* b_out  = (const float*)d_in[9];

    float* out = (float*)d_out;                  // pred_deltas (B,T,2)
    float* pos = out + (size_t)B_SZ * T_SZ * 2;  // pred_pos    (B,T,2)

    // ws layout (f16 units): hA (4M), hB (4M), wpk (3M), winit (1M) = 24 MB.
    // ev_f16 aliases hB (consumed by h0 before hB is first written).
    // After h0, the winit region (1M f16 = 2MB) is dead and is reused for:
    //   tT   (f16, 50*4096*2 = 409600 elems) at winit+0
    //   pA   (f32, 131072) at winit+417792, pB at winit+679936  (ends 942080)
    f16* ws = (f16*)d_ws;
    f16* hA    = ws;
    f16* hB    = hA + (size_t)B_SZ * H_SZ;
    f16* wpk   = hB + (size_t)B_SZ * H_SZ;
    f16* winit = wpk + (size_t)3 * H_SZ * H_SZ;
    f16* evf   = hB;  // alias
    f16* tT    = winit;
    float* pA  = (float*)(winit + 417792);
    float* pB  = pA + 131072;

    conv_kernel<<<(H_SZ * D_SZ) / 1024, 256, 0, stream>>>(w_init, winit, H_SZ * D_SZ);
    conv_kernel<<<(B_SZ * D_SZ) / 1024, 256, 0, stream>>>(ev, evf, B_SZ * D_SZ);
    prepack_kernel<<<dim3(3, 32, 16), 256, 0, stream>>>(w_hh, wpk);

    dim3 g0(H_SZ / 64, B_SZ / 128);  // (16, 32)
    h0_kernel<<<g0, 256, 0, stream>>>(evf, winit, b_init, hA);

    // winit consumed; build tT in its place
    ttrans_kernel<<<(T_SZ * B_SZ + 255) / 256, 256, 0, stream>>>(teach, tT);

    f16 *hc = hA, *hn = hB;
    for (int t = 0; t < T_SZ; ++t) {
        float* partC = (t & 1) ? pB : pA;
        float* partP = (t & 1) ? pA : pB;
        step_kernel<<<256, 512, 0, stream>>>(hc, wpk, b_hh, w_ih, b_ih, w_out,
                                             tT, hn, out, partP, partC, t);
        f16* tmp = hc; hc = hn; hn = tmp;
    }
    // t=49 is odd -> its partials are in pB
    final_kernel<<<(B_SZ * 2 + 255) / 256, 256, 0, stream>>>(out, pos, b_out, pB);
}